// Round 22
// baseline (40.300 us; speedup 1.0000x reference)
//
#include <hip/hip_runtime.h>

#define N_Q   50000
#define N_S   50000
#define M_NB  32
#define K_PTS 15
#define CIN   64
#define COUT  64
#define WPB   2
#define THR   0.0101f   // ||nb||^2 bound for any w>0 (exact: 0.009901)

// Event: racc gather of the weighted feature row, then wide GEMV.
// PROBE: a second GEMV against a DIFFERENT weight panel (wq2), result sunk —
// measures the marginal cost of the per-event 256-line weight read.
__device__ __forceinline__ void do_event(
    unsigned em, int laneoff, float w, int idx,
    float* bc, const float* wq, const float* wq2, int cg,
    const float* __restrict__ x, int lane, float4& tout)
{
    float racc = 0.f;
    do {
        const int src = laneoff + __builtin_ctz(em); em &= em - 1;
        const float wsrc = __shfl(w, src);
        const int   isrc = __builtin_amdgcn_readfirstlane(__shfl(idx, src));
        racc = fmaf(wsrc, x[(size_t)isrc * CIN + lane], racc);
    } while (em);
    bc[lane] = racc;
    asm volatile("" ::: "memory");

    // ---- real GEMV ----
    float4 a0 = make_float4(0.f, 0.f, 0.f, 0.f);
    float4 a1 = make_float4(0.f, 0.f, 0.f, 0.f);
    #pragma unroll
    for (int i = 0; i < 16; i += 2) {
        const float4 v0 = *(const float4*)(wq + (i + 0) * 4 * COUT);
        const float4 v1 = *(const float4*)(wq + (i + 1) * 4 * COUT);
        const float xc0 = bc[cg + 4 * i];
        const float xc1 = bc[cg + 4 * i + 4];
        a0.x = fmaf(xc0, v0.x, a0.x); a0.y = fmaf(xc0, v0.y, a0.y);
        a0.z = fmaf(xc0, v0.z, a0.z); a0.w = fmaf(xc0, v0.w, a0.w);
        a1.x = fmaf(xc1, v1.x, a1.x); a1.y = fmaf(xc1, v1.y, a1.y);
        a1.z = fmaf(xc1, v1.z, a1.z); a1.w = fmaf(xc1, v1.w, a1.w);
    }
    a0.x += a1.x; a0.y += a1.y; a0.z += a1.z; a0.w += a1.w;
    a0.x += __shfl_xor(a0.x, 16); a0.y += __shfl_xor(a0.y, 16);
    a0.z += __shfl_xor(a0.z, 16); a0.w += __shfl_xor(a0.w, 16);
    a0.x += __shfl_xor(a0.x, 32); a0.y += __shfl_xor(a0.y, 32);
    a0.z += __shfl_xor(a0.z, 32); a0.w += __shfl_xor(a0.w, 32);
    tout.x += a0.x; tout.y += a0.y; tout.z += a0.z; tout.w += a0.w;

    // ---- amplification GEMV (different panel, sunk result) ----
    float4 b0 = make_float4(0.f, 0.f, 0.f, 0.f);
    #pragma unroll
    for (int i = 0; i < 16; ++i) {
        const float4 v0 = *(const float4*)(wq2 + i * 4 * COUT);
        const float xc0 = bc[cg + 4 * i];
        b0.x = fmaf(xc0, v0.x, b0.x); b0.y = fmaf(xc0, v0.y, b0.y);
        b0.z = fmaf(xc0, v0.z, b0.z); b0.w = fmaf(xc0, v0.w, b0.w);
    }
    asm volatile("" :: "v"(b0.x), "v"(b0.y), "v"(b0.z), "v"(b0.w));

    asm volatile("" ::: "memory");
}

// R19 champion structure: one wave per TWO query points (A = lanes 0-31,
// B = lanes 32-63), scalar-path query loads, single dispatch, no workspace.
__global__ __launch_bounds__(128) void kpconv_probe(
    const float* __restrict__ query,     // [N,3]
    const float* __restrict__ support,   // [N0,3]
    const int*   __restrict__ neighbors, // [N,M]
    const float* __restrict__ x,         // [N0,CIN]
    const float* __restrict__ kpts,      // [K,3]
    const float* __restrict__ weight,    // [K,CIN,COUT]
    float*       __restrict__ out)       // [N,COUT]
{
    __shared__ float s_kx[K_PTS], s_ky[K_PTS], s_kz[K_PTS], s_kk[K_PTS];
    __shared__ float s_bc[WPB][CIN];

    const int tid = threadIdx.x;
    if (tid < K_PTS) {
        float kx = kpts[tid * 3 + 0];
        float ky = kpts[tid * 3 + 1];
        float kz = kpts[tid * 3 + 2];
        s_kx[tid] = kx; s_ky[tid] = ky; s_kz[tid] = kz;
        s_kk[tid] = kx * kx + ky * ky + kz * kz;   // same 3-term fp32 sum as ref
    }
    __syncthreads();

    const int wv   = __builtin_amdgcn_readfirstlane(tid >> 6);
    const int lane = tid & 63;
    const int base = blockIdx.x * (WPB * 2) + wv * 2;
    const int h    = lane >> 5;
    const int n    = base + h;
    const int m    = lane & 31;

    const float qxA = query[(base + 0) * 3 + 0];
    const float qyA = query[(base + 0) * 3 + 1];
    const float qzA = query[(base + 0) * 3 + 2];
    const float qxB = query[(base + 1) * 3 + 0];
    const float qyB = query[(base + 1) * 3 + 1];
    const float qzB = query[(base + 1) * 3 + 2];
    const float qx = h ? qxB : qxA;
    const float qy = h ? qyB : qyA;
    const float qz = h ? qzB : qzA;

    const int idx = neighbors[n * M_NB + m];

    float dx = 0.f, dy = 0.f, dz = 0.f, nn = 1e30f;
    if (idx < N_S) {
        dx = support[idx * 3 + 0] - qx;
        dy = support[idx * 3 + 1] - qy;
        dz = support[idx * 3 + 2] - qz;
        nn = dx * dx + dy * dy + dz * dz;
    }

    const int og = (lane & 15) * 4;
    const int cg = lane >> 4;

    float4 toutA = make_float4(0.f, 0.f, 0.f, 0.f);
    float4 toutB = make_float4(0.f, 0.f, 0.f, 0.f);

    if (__ballot(nn < THR)) {
        for (int k = 0; k < K_PTS; ++k) {
            float w = 0.f;
            if (nn < THR) {
                float dot = dx * s_kx[k] + dy * s_ky[k] + dz * s_kz[k];
                float sq  = fmaxf(nn - 2.f * dot + s_kk[k], 0.f);
                if (sq < 0.0025f)
                    w = 1.f - sqrtf(sq) * 20.f;
            }
            const unsigned long long em = __ballot(w > 0.f);
            if (!em) continue;

            const int k2 = (k + 7 >= K_PTS) ? k + 7 - K_PTS : k + 7;
            const float* wq  = weight + (size_t)k  * CIN * COUT + cg * COUT + og;
            const float* wq2 = weight + (size_t)k2 * CIN * COUT + cg * COUT + og;

            unsigned mm;
            if ((mm = (unsigned)(em & 0xffffffffull)))
                do_event(mm,  0, w, idx, s_bc[wv], wq, wq2, cg, x, lane, toutA);
            if ((mm = (unsigned)(em >> 32)))
                do_event(mm, 32, w, idx, s_bc[wv], wq, wq2, cg, x, lane, toutB);
        }
    }

    float4* rowA = (float4*)(out + (size_t)(base + 0) * COUT);
    float4* rowB = (float4*)(out + (size_t)(base + 1) * COUT);
    if (lane < 16)       rowA[lane]      = toutA;
    else if (lane < 32)  rowB[lane - 16] = toutB;
}

extern "C" void kernel_launch(void* const* d_in, const int* in_sizes, int n_in,
                              void* d_out, int out_size, void* d_ws, size_t ws_size,
                              hipStream_t stream) {
    const float* query     = (const float*)d_in[0];
    const float* support   = (const float*)d_in[1];
    const int*   neighbors = (const int*)  d_in[2];
    const float* x         = (const float*)d_in[3];
    const float* kpts      = (const float*)d_in[4];
    const float* weight    = (const float*)d_in[5];
    float*       out       = (float*)d_out;

    kpconv_probe<<<N_Q / 4, 128, 0, stream>>>(
        query, support, neighbors, x, kpts, weight, out);
}

// Round 23
// 28.617 us; speedup vs baseline: 1.4082x; 1.4082x over previous
//
#include <hip/hip_runtime.h>

#define N_Q   50000
#define N_S   50000
#define M_NB  32
#define K_PTS 15
#define CIN   64
#define COUT  64
#define WPB   2
#define THR   0.0101f   // ||nb||^2 bound for any w>0 (exact: 0.009901)

#define RED4(a)                                                      \
    a.x += __shfl_xor(a.x, 16); a.y += __shfl_xor(a.y, 16);          \
    a.z += __shfl_xor(a.z, 16); a.w += __shfl_xor(a.w, 16);          \
    a.x += __shfl_xor(a.x, 32); a.y += __shfl_xor(a.y, 32);          \
    a.z += __shfl_xor(a.z, 32); a.w += __shfl_xor(a.w, 32);

// R19 champion + (1) x-row prefetch at ballot time (R18) and
// (2) pending-pair GEMV: two events' 64x64 GEMVs fused into one 32-load
// interleaved pass (one L2 latency exposure instead of two).
// Per-event FMA/reduce order identical to R19 -> bit-identical output.
__global__ __launch_bounds__(128) void kpconv_fused9(
    const float* __restrict__ query,     // [N,3]
    const float* __restrict__ support,   // [N0,3]
    const int*   __restrict__ neighbors, // [N,M]
    const float* __restrict__ x,         // [N0,CIN]
    const float* __restrict__ kpts,      // [K,3]
    const float* __restrict__ weight,    // [K,CIN,COUT]
    float*       __restrict__ out)       // [N,COUT]
{
    __shared__ float s_kx[K_PTS], s_ky[K_PTS], s_kz[K_PTS], s_kk[K_PTS];
    __shared__ float s_r0[WPB][CIN], s_r1[WPB][CIN];

    const int tid = threadIdx.x;
    if (tid < K_PTS) {
        float kx = kpts[tid * 3 + 0];
        float ky = kpts[tid * 3 + 1];
        float kz = kpts[tid * 3 + 2];
        s_kx[tid] = kx; s_ky[tid] = ky; s_kz[tid] = kz;
        s_kk[tid] = kx * kx + ky * ky + kz * kz;   // same 3-term fp32 sum as ref
    }
    __syncthreads();

    const int wv   = __builtin_amdgcn_readfirstlane(tid >> 6);  // uniform SGPR
    const int lane = tid & 63;
    const int base = blockIdx.x * (WPB * 2) + wv * 2;
    const int h    = lane >> 5;
    const int n    = base + h;
    const int m    = lane & 31;

    // scalar (SMEM) query loads: uniform addresses
    const float qxA = query[(base + 0) * 3 + 0];
    const float qyA = query[(base + 0) * 3 + 1];
    const float qzA = query[(base + 0) * 3 + 2];
    const float qxB = query[(base + 1) * 3 + 0];
    const float qyB = query[(base + 1) * 3 + 1];
    const float qzB = query[(base + 1) * 3 + 2];
    const float qx = h ? qxB : qxA;
    const float qy = h ? qyB : qyA;
    const float qz = h ? qzB : qzA;

    const int idx = neighbors[n * M_NB + m];       // coalesced (2 rows/wave)

    float dx = 0.f, dy = 0.f, dz = 0.f, nn = 1e30f;
    if (idx < N_S) {                               // idx==N_S: shadow, w==0
        dx = support[idx * 3 + 0] - qx;
        dy = support[idx * 3 + 1] - qy;
        dz = support[idx * 3 + 2] - qz;
        nn = dx * dx + dy * dy + dz * dz;
    }

    const int og = (lane & 15) * 4;
    const int cg = lane >> 4;

    float4 toutA = make_float4(0.f, 0.f, 0.f, 0.f);
    float4 toutB = make_float4(0.f, 0.f, 0.f, 0.f);

    const unsigned long long cb = __ballot(nn < THR);

    if (cb) {                                      // ~23% of waves
        // ---- prefetch up to 4 close x-rows (wave-uniform srcs, MLP=4) ----
        unsigned long long t = cb;
        int s0 = -1, s1 = -1, s2 = -1, s3 = -1;
        if (t) { s0 = __ffsll(t) - 1; t &= t - 1; }
        if (t) { s1 = __ffsll(t) - 1; t &= t - 1; }
        if (t) { s2 = __ffsll(t) - 1; t &= t - 1; }
        if (t) { s3 = __ffsll(t) - 1; t &= t - 1; }
        float xr0 = 0.f, xr1 = 0.f, xr2 = 0.f, xr3 = 0.f;
        if (s0 >= 0) xr0 = x[(size_t)__builtin_amdgcn_readfirstlane(__shfl(idx, s0)) * CIN + lane];
        if (s1 >= 0) xr1 = x[(size_t)__builtin_amdgcn_readfirstlane(__shfl(idx, s1)) * CIN + lane];
        if (s2 >= 0) xr2 = x[(size_t)__builtin_amdgcn_readfirstlane(__shfl(idx, s2)) * CIN + lane];
        if (s3 >= 0) xr3 = x[(size_t)__builtin_amdgcn_readfirstlane(__shfl(idx, s3)) * CIN + lane];

        int havePend = 0, pk = 0, pB = 0;          // wave-uniform state

        for (int k = 0; k < K_PTS; ++k) {
            float w = 0.f;
            if (nn < THR) {
                float dot = dx * s_kx[k] + dy * s_ky[k] + dz * s_kz[k];
                float sq  = fmaxf(nn - 2.f * dot + s_kk[k], 0.f);  // ref expansion
                if (sq < 0.0025f)                   // sqrt(sq) < 0.05 => w > 0
                    w = 1.f - sqrtf(sq) * 20.f;     // 1/0.05 == 20 exactly
            }
            const unsigned long long em = __ballot(w > 0.f);
            if (!em) continue;                      // common: k has no hits

            #pragma unroll
            for (int half = 0; half < 2; ++half) {
                unsigned mm = half ? (unsigned)(em >> 32)
                                   : (unsigned)(em & 0xffffffffull);
                if (!mm) continue;
                const int off = half * 32;

                float racc = 0.f;
                do {
                    const int src = off + __builtin_ctz(mm); mm &= mm - 1;
                    const float wsrc = __shfl(w, src);
                    float xv;
                    if      (src == s0) xv = xr0;
                    else if (src == s1) xv = xr1;
                    else if (src == s2) xv = xr2;
                    else if (src == s3) xv = xr3;
                    else xv = x[(size_t)__builtin_amdgcn_readfirstlane(
                                   __shfl(idx, src)) * CIN + lane];
                    racc = fmaf(wsrc, xv, racc);
                } while (mm);

                if (!havePend) {                    // buffer first event
                    s_r0[wv][lane] = racc;
                    asm volatile("" ::: "memory");
                    pk = k; pB = half; havePend = 1;
                } else {                            // fused 2-event GEMV
                    s_r1[wv][lane] = racc;
                    asm volatile("" ::: "memory");
                    const float* wqa = weight + (size_t)pk * CIN * COUT + cg * COUT + og;
                    const float* wqb = weight + (size_t)k  * CIN * COUT + cg * COUT + og;
                    float4 a0 = make_float4(0.f,0.f,0.f,0.f);
                    float4 a1 = make_float4(0.f,0.f,0.f,0.f);
                    float4 b0 = make_float4(0.f,0.f,0.f,0.f);
                    float4 b1 = make_float4(0.f,0.f,0.f,0.f);
                    #pragma unroll
                    for (int i = 0; i < 16; i += 2) {
                        const float4 va0 = *(const float4*)(wqa + (i + 0) * 4 * COUT);
                        const float4 va1 = *(const float4*)(wqa + (i + 1) * 4 * COUT);
                        const float4 vb0 = *(const float4*)(wqb + (i + 0) * 4 * COUT);
                        const float4 vb1 = *(const float4*)(wqb + (i + 1) * 4 * COUT);
                        const float xa0 = s_r0[wv][cg + 4 * i];
                        const float xa1 = s_r0[wv][cg + 4 * i + 4];
                        const float xb0 = s_r1[wv][cg + 4 * i];
                        const float xb1 = s_r1[wv][cg + 4 * i + 4];
                        a0.x = fmaf(xa0, va0.x, a0.x); a0.y = fmaf(xa0, va0.y, a0.y);
                        a0.z = fmaf(xa0, va0.z, a0.z); a0.w = fmaf(xa0, va0.w, a0.w);
                        a1.x = fmaf(xa1, va1.x, a1.x); a1.y = fmaf(xa1, va1.y, a1.y);
                        a1.z = fmaf(xa1, va1.z, a1.z); a1.w = fmaf(xa1, va1.w, a1.w);
                        b0.x = fmaf(xb0, vb0.x, b0.x); b0.y = fmaf(xb0, vb0.y, b0.y);
                        b0.z = fmaf(xb0, vb0.z, b0.z); b0.w = fmaf(xb0, vb0.w, b0.w);
                        b1.x = fmaf(xb1, vb1.x, b1.x); b1.y = fmaf(xb1, vb1.y, b1.y);
                        b1.z = fmaf(xb1, vb1.z, b1.z); b1.w = fmaf(xb1, vb1.w, b1.w);
                    }
                    a0.x += a1.x; a0.y += a1.y; a0.z += a1.z; a0.w += a1.w;
                    b0.x += b1.x; b0.y += b1.y; b0.z += b1.z; b0.w += b1.w;
                    RED4(a0); RED4(b0);
                    if (pB) { toutB.x += a0.x; toutB.y += a0.y; toutB.z += a0.z; toutB.w += a0.w; }
                    else    { toutA.x += a0.x; toutA.y += a0.y; toutA.z += a0.z; toutA.w += a0.w; }
                    if (half) { toutB.x += b0.x; toutB.y += b0.y; toutB.z += b0.z; toutB.w += b0.w; }
                    else      { toutA.x += b0.x; toutA.y += b0.y; toutA.z += b0.z; toutA.w += b0.w; }
                    havePend = 0;
                    asm volatile("" ::: "memory");
                }
            }
        }

        if (havePend) {                             // leftover single event
            const float* wqa = weight + (size_t)pk * CIN * COUT + cg * COUT + og;
            float4 a0 = make_float4(0.f,0.f,0.f,0.f);
            float4 a1 = make_float4(0.f,0.f,0.f,0.f);
            #pragma unroll
            for (int i = 0; i < 16; i += 2) {
                const float4 va0 = *(const float4*)(wqa + (i + 0) * 4 * COUT);
                const float4 va1 = *(const float4*)(wqa + (i + 1) * 4 * COUT);
                const float xa0 = s_r0[wv][cg + 4 * i];
                const float xa1 = s_r0[wv][cg + 4 * i + 4];
                a0.x = fmaf(xa0, va0.x, a0.x); a0.y = fmaf(xa0, va0.y, a0.y);
                a0.z = fmaf(xa0, va0.z, a0.z); a0.w = fmaf(xa0, va0.w, a0.w);
                a1.x = fmaf(xa1, va1.x, a1.x); a1.y = fmaf(xa1, va1.y, a1.y);
                a1.z = fmaf(xa1, va1.z, a1.z); a1.w = fmaf(xa1, va1.w, a1.w);
            }
            a0.x += a1.x; a0.y += a1.y; a0.z += a1.z; a0.w += a1.w;
            RED4(a0);
            if (pB) { toutB.x += a0.x; toutB.y += a0.y; toutB.z += a0.z; toutB.w += a0.w; }
            else    { toutA.x += a0.x; toutA.y += a0.y; toutA.z += a0.z; toutA.w += a0.w; }
        }
    }

    float4* rowA = (float4*)(out + (size_t)(base + 0) * COUT);
    float4* rowB = (float4*)(out + (size_t)(base + 1) * COUT);
    if (lane < 16)       rowA[lane]      = toutA;
    else if (lane < 32)  rowB[lane - 16] = toutB;
}

extern "C" void kernel_launch(void* const* d_in, const int* in_sizes, int n_in,
                              void* d_out, int out_size, void* d_ws, size_t ws_size,
                              hipStream_t stream) {
    const float* query     = (const float*)d_in[0];
    const float* support   = (const float*)d_in[1];
    const int*   neighbors = (const int*)  d_in[2];
    const float* x         = (const float*)d_in[3];
    const float* kpts      = (const float*)d_in[4];
    const float* weight    = (const float*)d_in[5];
    float*       out       = (float*)d_out;

    kpconv_fused9<<<N_Q / 4, 128, 0, stream>>>(    // 12500 blocks, 2 waves
        query, support, neighbors, x, kpts, weight, out);
}